// Round 14
// baseline (129.583 us; speedup 1.0000x reference)
//
#include <hip/hip_runtime.h>

// QMixer — round 14: traffic reduction (the ~7TB/s L3 serve-rate wall).
// Evidence: r5 870MB/124.8us, r13 720MB/101.5us, r12 vs r13 structure-insensitive
// => weight-broadcast streams served at ~7TB/s. Only traffic cuts help.
//  - K2: 192-row blocks (LDS 158KB: h1s 96 + bbuf 32 single + q_t 25) ->
//    B traffic 268->172MB. 171 blocks, tail clamps loads/masks stores.
//    2 barriers/agent, per-agent A ds_reads (VGPR ~105, law-safe).
//  - K1: r13 verbatim + 3-bit slot-XOR fixing the 4-way B-read bank conflict.

#define SDIM 512
#define HD   256
#define EDIM 64
#define NAG  32
#define R2   192            // K2 rows per block
#define NROW 32768

typedef short short8v __attribute__((ext_vector_type(8)));
typedef short short4v __attribute__((ext_vector_type(4)));
typedef float f32x4  __attribute__((ext_vector_type(4)));

__device__ __forceinline__ unsigned short f2bf(float f) {
  unsigned int u = __float_as_uint(f);
  unsigned int r = (u + 0x7FFFu + ((u >> 16) & 1u)) >> 16;
  return (unsigned short)r;
}
__device__ __forceinline__ float bf2f(unsigned short u) {
  return __uint_as_float(((unsigned int)u) << 16);
}
__device__ __forceinline__ short4v cvt4(float4 a) {
  short4v r;
  r[0] = (short)f2bf(a.x); r[1] = (short)f2bf(a.y);
  r[2] = (short)f2bf(a.z); r[3] = (short)f2bf(a.w);
  return r;
}

// ---------------- convert weights to bf16 ----------------
__global__ void qmix_convert(const float* __restrict__ w1_0, const float* __restrict__ wf_0,
                             const float* __restrict__ hb_w, const float* __restrict__ v0_w,
                             const float* __restrict__ w1_2, const float* __restrict__ wf_2,
                             unsigned short* __restrict__ W0cat, unsigned short* __restrict__ w12b,
                             unsigned short* __restrict__ wf2b) {
  int i = blockIdx.x * 256 + threadIdx.x;
  if (i < 327680) {
    float v;
    if (i < 131072)      v = w1_0[i];
    else if (i < 262144) v = wf_0[i - 131072];
    else if (i < 294912) v = hb_w[i - 262144];
    else                 v = v0_w[i - 294912];
    W0cat[i] = f2bf(v);
  } else if (i < 851968) {
    w12b[i - 327680] = f2bf(w1_2[i - 327680]);
  } else if (i < 868352) {
    wf2b[i - 851968] = f2bf(wf_2[i - 851968]);
  }
}

// ---------------- K1: gemm1 + wf + heads, 64-row blocks, B-in-LDS dbuf ----------------
__global__ __launch_bounds__(512, 1) void qmix_k1(
    const float* __restrict__ states, const unsigned short* __restrict__ W0cat,
    const unsigned short* __restrict__ wf2b,
    const float* __restrict__ b1_0, const float* __restrict__ bf_0,
    const float* __restrict__ hb_b, const float* __restrict__ v0_b,
    const float* __restrict__ v2_w, const float* __restrict__ bf_2,
    unsigned short* __restrict__ h1g, unsigned short* __restrict__ b1h,
    unsigned short* __restrict__ wfinh, float* __restrict__ vbuf)
{
  __shared__ unsigned short sA[64 * 512];      // 64 KB: states, then h1|hf (swizzled)
  __shared__ unsigned short bbuf[2][20480];    // 80 KB: B k-slice dbuf [col][32k], slot-XOR swz

  const int t    = threadIdx.x;
  const int r0   = blockIdx.x * 64;
  const int wave = t >> 6, lane = t & 63;
  const int lrow = lane & 15, lk = lane >> 4;
  const int rg = wave >> 2;      // row-half 0..1 (32 rows)
  const int ch = wave & 3;       // col-quarter 0..3 (160 cols)
  const int colbase = ch * 160;

  // ---- phase 0: issue all loads (states + B slice 0), then LDS writes ----
  const float4* gS4 = (const float4*)(states + (size_t)r0 * SDIM);
  float4 L[16];
#pragma unroll
  for (int it = 0; it < 16; it++) L[it] = gS4[it * 512 + t];

  short8v breg[5];
#pragma unroll
  for (int j = 0; j < 5; j++) {
    int m = j * 512 + t;                // 2560 chunks of 16B = 40 KB
    int col = m >> 2, kslot = m & 3;
    breg[j] = *(const short8v*)(W0cat + (size_t)col * SDIM + kslot * 8);
  }

#pragma unroll
  for (int it = 0; it < 16; it++) {
    int idx = it * 512 + t;
    int row = idx >> 7, c4 = idx & 127;
    int byte = (row * 1024 + c4 * 8) ^ ((row & 7) << 4);
    *(short4v*)((char*)sA + byte) = cvt4(L[it]);
  }
#pragma unroll
  for (int j = 0; j < 5; j++) {
    int m = j * 512 + t;
    int col = m >> 2, kslot = m & 3;
    int slot = kslot ^ (col & 3) ^ ((col >> 2) & 3);
    *(short8v*)((char*)bbuf + col * 64 + (slot << 4)) = breg[j];
  }
  __syncthreads();   // bar1: states + B slice 0 staged

  // ---- k-loop: acc[2][10], B from LDS (each read feeds 2 MFMA) ----
  f32x4 acc[2][10];
#pragma unroll
  for (int i = 0; i < 2; i++)
#pragma unroll
    for (int f = 0; f < 10; f++) acc[i][f] = (f32x4){0.f, 0.f, 0.f, 0.f};

#pragma unroll 1
  for (int ks = 0; ks < 16; ks++) {
    if (ks < 15) {
#pragma unroll
      for (int j = 0; j < 5; j++) {
        int m = j * 512 + t;
        int col = m >> 2, kslot = m & 3;
        breg[j] = *(const short8v*)(W0cat + (size_t)col * SDIM + (ks + 1) * 32 + kslot * 8);
      }
    }
    const char* rb = (const char*)bbuf + (ks & 1) * 40960;
    short8v af0, af1;
    {
      int row = rg * 32 + lrow;
      af0 = *(const short8v*)((const char*)sA + ((row * 1024 + ks * 64 + lk * 16) ^ ((row & 7) << 4)));
      row = rg * 32 + 16 + lrow;
      af1 = *(const short8v*)((const char*)sA + ((row * 1024 + ks * 64 + lk * 16) ^ ((row & 7) << 4)));
    }
#pragma unroll
    for (int cf = 0; cf < 10; cf++) {
      int col = colbase + cf * 16 + lrow;
      int slot = lk ^ (col & 3) ^ ((col >> 2) & 3);
      short8v b = *(const short8v*)(rb + col * 64 + (slot << 4));
      acc[0][cf] = __builtin_amdgcn_mfma_f32_16x16x32_bf16(af0, b, acc[0][cf], 0, 0, 0);
      acc[1][cf] = __builtin_amdgcn_mfma_f32_16x16x32_bf16(af1, b, acc[1][cf], 0, 0, 0);
    }
    if (ks < 15) {
      char* wb = (char*)bbuf + ((ks + 1) & 1) * 40960;
#pragma unroll
      for (int j = 0; j < 5; j++) {
        int m = j * 512 + t;
        int col = m >> 2, kslot = m & 3;
        int slot = kslot ^ (col & 3) ^ ((col >> 2) & 3);
        *(short8v*)(wb + col * 64 + (slot << 4)) = breg[j];
      }
    }
    __syncthreads();
  }

  // ---- epilogue: heads by column range, h written back into sA ----
  {
    float vs[2][4];
#pragma unroll
    for (int i = 0; i < 2; i++)
#pragma unroll
      for (int rr = 0; rr < 4; rr++) vs[i][rr] = 0.f;

#pragma unroll
    for (int cf = 0; cf < 10; cf++) {
      int cb  = colbase + cf * 16;   // wave-uniform
      int col = cb + lrow;
      if (cb < 512) {
        float bv = (cb < 256) ? b1_0[col] : bf_0[col - 256];
#pragma unroll
        for (int i = 0; i < 2; i++)
#pragma unroll
          for (int rr = 0; rr < 4; rr++) {
            int row = rg * 32 + i * 16 + lk * 4 + rr;
            float v = fmaxf(acc[i][cf][rr] + bv, 0.f);
            int byte = (row * 1024 + col * 2) ^ ((row & 7) << 4);
            *(unsigned short*)((char*)sA + byte) = f2bf(v);
          }
      } else if (cb < 576) {
        int e = col - 512;
        float bv = hb_b[e];
#pragma unroll
        for (int i = 0; i < 2; i++)
#pragma unroll
          for (int rr = 0; rr < 4; rr++) {
            int row = rg * 32 + i * 16 + lk * 4 + rr;
            b1h[(size_t)(r0 + row) * EDIM + e] = f2bf(acc[i][cf][rr] + bv);
          }
      } else {
        int e = col - 576;
        float bv = v0_b[e], wv = v2_w[e];
#pragma unroll
        for (int i = 0; i < 2; i++)
#pragma unroll
          for (int rr = 0; rr < 4; rr++)
            vs[i][rr] = fmaf(fmaxf(acc[i][cf][rr] + bv, 0.f), wv, vs[i][rr]);
      }
    }
    if (ch == 3) {
#pragma unroll
      for (int i = 0; i < 2; i++)
#pragma unroll
        for (int rr = 0; rr < 4; rr++) {
          float v = vs[i][rr];
#pragma unroll
          for (int m = 1; m < 16; m <<= 1) v += __shfl_xor(v, m, 64);
          if (lrow == 0) vbuf[r0 + rg * 32 + i * 16 + lk * 4 + rr] = v;
        }
    }
  }
  __syncthreads();   // h-tile complete

  // ---- wf head: waves = 4 row-frags x 2 e-halves over 64 rows ----
  {
    const int wr2 = wave >> 1;
    const int wc2 = wave & 1;
    f32x4 wfa[2];
    wfa[0] = (f32x4){0.f, 0.f, 0.f, 0.f};
    wfa[1] = (f32x4){0.f, 0.f, 0.f, 0.f};
    const int row = wr2 * 16 + lrow;
#pragma unroll
    for (int kf = 0; kf < 8; kf++) {
      int byte = (row * 1024 + 512 + kf * 64 + lk * 16) ^ ((row & 7) << 4);
      short8v af2 = *(const short8v*)((const char*)sA + byte);
#pragma unroll
      for (int j = 0; j < 2; j++) {
        short8v bf2v = *(const short8v*)(wf2b + (size_t)(wc2 * 32 + j * 16 + lrow) * HD + kf * 32 + 8 * lk);
        wfa[j] = __builtin_amdgcn_mfma_f32_16x16x32_bf16(af2, bf2v, wfa[j], 0, 0, 0);
      }
    }
#pragma unroll
    for (int j = 0; j < 2; j++) {
      int e = wc2 * 32 + j * 16 + lrow;
#pragma unroll
      for (int r = 0; r < 4; r++) {
        int row2 = wr2 * 16 + lk * 4 + r;
        wfinh[(size_t)(r0 + row2) * EDIM + e] = f2bf(fabsf(wfa[j][r] + bf_2[e]));
      }
    }
  }

  // ---- h1 repack to HBM (swizzle baked into layout) ----
  {
    char* dst = (char*)h1g + (size_t)r0 * 512;
#pragma unroll
    for (int u = 0; u < 4; u++) {
      int idx = u * 512 + t;
      int row = idx >> 5;
      int p   = (idx & 31) * 16;
      short8v v = *(const short8v*)((const char*)sA + row * 1024 + p);
      *(short8v*)(dst + row * 512 + p) = v;
    }
  }
}

// ---------------- K2: gemm2 + mix, 192-row blocks, single-buffer agents ----------------
__global__ __launch_bounds__(512, 1) void qmix_k2(
    const unsigned short* __restrict__ h1g, const unsigned short* __restrict__ w12b,
    const float* __restrict__ agent_qs, const float* __restrict__ b1_2,
    const unsigned short* __restrict__ b1h, const unsigned short* __restrict__ wfinh,
    const float* __restrict__ vbuf, const float* __restrict__ v2_b,
    float* __restrict__ out)
{
  __shared__ unsigned char h1s[R2 * 512];      // 96 KB (pre-swizzled bf16 [192][256])
  __shared__ unsigned short bbuf[16384];       // 32 KB single-buffered agent tile
  __shared__ float q_t[NAG * 200];             // 25.6 KB q^T [agent][row(192)+pad]
  __shared__ float ypart[2][R2];               // 1.5 KB

  const int t    = threadIdx.x;
  const int r0   = blockIdx.x * R2;
  const int wave = t >> 6, lane = t & 63;
  const int lrow = lane & 15, lk = lane >> 4;
  const int wr = wave >> 1;    // rowgroup 0..3 (48 rows each)
  const int wc = wave & 1;     // e-half

  // ---- phase 0: stage h1 (clamped), q^T (clamped), agent 0 ----
  {
    short8v Lh[12];
#pragma unroll
    for (int it = 0; it < 12; it++) {
      int c = it * 512 + t;                 // 6144 chunks of 16B
      int row = c >> 5;
      int p   = (c & 31) * 16;
      long grow = r0 + row; if (grow > NROW - 1) grow = NROW - 1;
      Lh[it] = *(const short8v*)((const char*)h1g + grow * 512 + p);
    }
#pragma unroll
    for (int it = 0; it < 12; it++) {
      int c = it * 512 + t;
      *(short8v*)(h1s + c * 16) = Lh[it];
    }
  }
  {
    const float4* gq = (const float4*)agent_qs;
#pragma unroll
    for (int v = 0; v < 3; v++) {
      int idx = v * 512 + t;                // 1536 float4
      int row = idx >> 3, c4 = (idx & 7) * 4;
      long grow = r0 + row; if (grow > NROW - 1) grow = NROW - 1;
      float4 qv = gq[grow * 8 + (idx & 7)];
      q_t[(c4 + 0) * 200 + row] = qv.x;
      q_t[(c4 + 1) * 200 + row] = qv.y;
      q_t[(c4 + 2) * 200 + row] = qv.z;
      q_t[(c4 + 3) * 200 + row] = qv.w;
    }
  }
  short8v sreg[4];
#pragma unroll
  for (int rd = 0; rd < 4; rd++)
    sreg[rd] = *(const short8v*)(w12b + rd * 4096 + t * 8);   // agent 0
  {
#pragma unroll
    for (int rd = 0; rd < 4; rd++) {
      int Lo = rd * 8192 + t * 16;
      *(short8v*)((char*)bbuf + (Lo ^ (((Lo >> 9) & 7) << 4))) = sreg[rd];
    }
  }
  __syncthreads();   // h1s, q_t, bbuf(agent0) ready

  f32x4 hac[3][2];
#pragma unroll
  for (int i = 0; i < 3; i++) {
    hac[i][0] = (f32x4){0.f,0.f,0.f,0.f};
    hac[i][1] = (f32x4){0.f,0.f,0.f,0.f};
  }

  const int e0 = wc * 32 + lrow, e1 = e0 + 16;

#pragma unroll 1
  for (int a = 0; a < NAG; a++) {
    // issue next agent's loads (full compute phase of latency cover)
    if (a < NAG - 1) {
      const unsigned short* p = w12b + (size_t)(a + 1) * 16384;
#pragma unroll
      for (int rd = 0; rd < 4; rd++)
        sreg[rd] = *(const short8v*)(p + rd * 4096 + t * 8);
    }

    f32x4 T[3][2];
#pragma unroll
    for (int i = 0; i < 3; i++) {
      T[i][0] = (f32x4){0.f,0.f,0.f,0.f};
      T[i][1] = (f32x4){0.f,0.f,0.f,0.f};
    }
#pragma unroll
    for (int kf = 0; kf < 8; kf++) {
      short8v b0  = *(const short8v*)((const char*)bbuf + ((e0 * 512 + kf * 64 + lk * 16) ^ ((e0 & 7) << 4)));
      short8v b1v = *(const short8v*)((const char*)bbuf + ((e1 * 512 + kf * 64 + lk * 16) ^ ((e1 & 7) << 4)));
#pragma unroll
      for (int i = 0; i < 3; i++) {
        int row = wr * 48 + i * 16 + lrow;
        short8v af = *(const short8v*)(h1s + row * 512 + ((kf * 64 + lk * 16) ^ ((row & 7) << 4)));
        T[i][0] = __builtin_amdgcn_mfma_f32_16x16x32_bf16(af, b0,  T[i][0], 0, 0, 0);
        T[i][1] = __builtin_amdgcn_mfma_f32_16x16x32_bf16(af, b1v, T[i][1], 0, 0, 0);
      }
    }
    float bb0 = b1_2[a * EDIM + e0];
    float bb1 = b1_2[a * EDIM + e1];
#pragma unroll
    for (int i = 0; i < 3; i++) {
#pragma unroll
      for (int r = 0; r < 4; r++) {
        float qv = q_t[a * 200 + wr * 48 + i * 16 + lk * 4 + r];
        hac[i][0][r] = fmaf(qv, fabsf(T[i][0][r] + bb0), hac[i][0][r]);
        hac[i][1][r] = fmaf(qv, fabsf(T[i][1][r] + bb1), hac[i][1][r]);
      }
    }
    __syncthreads();             // all waves done reading bbuf
    if (a < NAG - 1) {
#pragma unroll
      for (int rd = 0; rd < 4; rd++) {
        int Lo = rd * 8192 + t * 16;
        *(short8v*)((char*)bbuf + (Lo ^ (((Lo >> 9) & 7) << 4))) = sreg[rd];
      }
    }
    __syncthreads();             // next agent staged
  }

  // ---- epilogue: elu(hid + b1)*wfin, reduce over e-half ----
  {
    float ys[3][4];
#pragma unroll
    for (int i = 0; i < 3; i++)
#pragma unroll
      for (int r = 0; r < 4; r++) {
        int row = wr * 48 + i * 16 + lk * 4 + r;
        long grow = r0 + row; if (grow > NROW - 1) grow = NROW - 1;
        size_t g = (size_t)grow * EDIM;
        float p0 = hac[i][0][r] + bf2f(b1h[g + e0]);
        float p1 = hac[i][1][r] + bf2f(b1h[g + e1]);
        float h0 = p0 > 0.f ? p0 : expm1f(p0);
        float h1 = p1 > 0.f ? p1 : expm1f(p1);
        ys[i][r] = h0 * bf2f(wfinh[g + e0]) + h1 * bf2f(wfinh[g + e1]);
      }
#pragma unroll
    for (int m = 1; m < 16; m <<= 1)
#pragma unroll
      for (int i = 0; i < 3; i++)
#pragma unroll
        for (int r = 0; r < 4; r++) ys[i][r] += __shfl_xor(ys[i][r], m, 64);
    if (lrow == 0) {
#pragma unroll
      for (int i = 0; i < 3; i++)
#pragma unroll
        for (int r = 0; r < 4; r++)
          ypart[wc][wr * 48 + i * 16 + lk * 4 + r] = ys[i][r];
    }
  }
  __syncthreads();
  if (t < R2) {
    long grow = r0 + t;
    if (grow < NROW)
      out[grow] = ypart[0][t] + ypart[1][t] + vbuf[grow] + v2_b[0];
  }
}

extern "C" void kernel_launch(void* const* d_in, const int* in_sizes, int n_in,
                              void* d_out, int out_size, void* d_ws, size_t ws_size,
                              hipStream_t stream) {
  const float* agent_qs = (const float*)d_in[0];
  const float* states   = (const float*)d_in[1];
  const float* w1_0 = (const float*)d_in[2];
  const float* b1_0 = (const float*)d_in[3];
  const float* w1_2 = (const float*)d_in[4];
  const float* b1_2 = (const float*)d_in[5];
  const float* wf_0 = (const float*)d_in[6];
  const float* bf_0 = (const float*)d_in[7];
  const float* wf_2 = (const float*)d_in[8];
  const float* bf_2 = (const float*)d_in[9];
  const float* hb_w = (const float*)d_in[10];
  const float* hb_b = (const float*)d_in[11];
  const float* v0_w = (const float*)d_in[12];
  const float* v0_b = (const float*)d_in[13];
  const float* v2_w = (const float*)d_in[14];
  const float* v2_b = (const float*)d_in[15];

  char* ws = (char*)d_ws;
  unsigned short* W0cat = (unsigned short*)ws;                  //    655,360 B
  unsigned short* w12b  = (unsigned short*)(ws + 655360);       //  1,048,576 B
  unsigned short* wf2b  = (unsigned short*)(ws + 1703936);      //     32,768 B
  unsigned short* h1g   = (unsigned short*)(ws + 1736704);      // 16,777,216 B
  unsigned short* b1h   = (unsigned short*)(ws + 18513920);     //  4,194,304 B
  unsigned short* wfinh = (unsigned short*)(ws + 22708224);     //  4,194,304 B
  float*          vbuf  = (float*)(ws + 26902528);              //    131,072 B

  qmix_convert<<<3392, 256, 0, stream>>>(w1_0, wf_0, hb_w, v0_w, w1_2, wf_2,
                                         W0cat, w12b, wf2b);
  qmix_k1<<<512, 512, 0, stream>>>(states, W0cat, wf2b, b1_0, bf_0, hb_b, v0_b,
                                   v2_w, bf_2, h1g, b1h, wfinh, vbuf);
  qmix_k2<<<(NROW + R2 - 1) / R2, 512, 0, stream>>>(h1g, w12b, agent_qs, b1_2,
                                                    b1h, wfinh, vbuf, v2_b,
                                                    (float*)d_out);
}

// Round 15
// 107.055 us; speedup vs baseline: 1.2104x; 1.2104x over previous
//
#include <hip/hip_runtime.h>

// QMixer — round 15: recombination of proven-best halves.
//   K1 = r14's (64-row, B-in-LDS dbuf, slot-XOR conflict fix) — inferred ~52us.
//   K2 = r9's verbatim (128-row, register-hoisted A, dbuf, 1 barrier/agent,
//        ~35us — near its LDS-BW floor; r14's 192-row variant regressed by
//        trading reg-A for LDS-A + 2 barrier drains/agent).

#define SDIM 512
#define HD   256
#define EDIM 64
#define NAG  32

typedef short short8v __attribute__((ext_vector_type(8)));
typedef short short4v __attribute__((ext_vector_type(4)));
typedef float f32x4  __attribute__((ext_vector_type(4)));

__device__ __forceinline__ unsigned short f2bf(float f) {
  unsigned int u = __float_as_uint(f);
  unsigned int r = (u + 0x7FFFu + ((u >> 16) & 1u)) >> 16;
  return (unsigned short)r;
}
__device__ __forceinline__ float bf2f(unsigned short u) {
  return __uint_as_float(((unsigned int)u) << 16);
}
__device__ __forceinline__ short4v cvt4(float4 a) {
  short4v r;
  r[0] = (short)f2bf(a.x); r[1] = (short)f2bf(a.y);
  r[2] = (short)f2bf(a.z); r[3] = (short)f2bf(a.w);
  return r;
}

// ---------------- convert weights to bf16 ----------------
__global__ void qmix_convert(const float* __restrict__ w1_0, const float* __restrict__ wf_0,
                             const float* __restrict__ hb_w, const float* __restrict__ v0_w,
                             const float* __restrict__ w1_2, const float* __restrict__ wf_2,
                             unsigned short* __restrict__ W0cat, unsigned short* __restrict__ w12b,
                             unsigned short* __restrict__ wf2b) {
  int i = blockIdx.x * 256 + threadIdx.x;
  if (i < 327680) {
    float v;
    if (i < 131072)      v = w1_0[i];
    else if (i < 262144) v = wf_0[i - 131072];
    else if (i < 294912) v = hb_w[i - 262144];
    else                 v = v0_w[i - 294912];
    W0cat[i] = f2bf(v);
  } else if (i < 851968) {
    w12b[i - 327680] = f2bf(w1_2[i - 327680]);
  } else if (i < 868352) {
    wf2b[i - 851968] = f2bf(wf_2[i - 851968]);
  }
}

// ---------------- K1: gemm1 + wf + heads, 64-row blocks, B-in-LDS dbuf (r14) ----------------
__global__ __launch_bounds__(512, 1) void qmix_k1(
    const float* __restrict__ states, const unsigned short* __restrict__ W0cat,
    const unsigned short* __restrict__ wf2b,
    const float* __restrict__ b1_0, const float* __restrict__ bf_0,
    const float* __restrict__ hb_b, const float* __restrict__ v0_b,
    const float* __restrict__ v2_w, const float* __restrict__ bf_2,
    unsigned short* __restrict__ h1g, unsigned short* __restrict__ b1h,
    unsigned short* __restrict__ wfinh, float* __restrict__ vbuf)
{
  __shared__ unsigned short sA[64 * 512];      // 64 KB: states, then h1|hf (swizzled)
  __shared__ unsigned short bbuf[2][20480];    // 80 KB: B k-slice dbuf, slot-XOR swz

  const int t    = threadIdx.x;
  const int r0   = blockIdx.x * 64;
  const int wave = t >> 6, lane = t & 63;
  const int lrow = lane & 15, lk = lane >> 4;
  const int rg = wave >> 2;      // row-half 0..1 (32 rows)
  const int ch = wave & 3;       // col-quarter 0..3 (160 cols)
  const int colbase = ch * 160;

  const float4* gS4 = (const float4*)(states + (size_t)r0 * SDIM);
  float4 L[16];
#pragma unroll
  for (int it = 0; it < 16; it++) L[it] = gS4[it * 512 + t];

  short8v breg[5];
#pragma unroll
  for (int j = 0; j < 5; j++) {
    int m = j * 512 + t;
    int col = m >> 2, kslot = m & 3;
    breg[j] = *(const short8v*)(W0cat + (size_t)col * SDIM + kslot * 8);
  }

#pragma unroll
  for (int it = 0; it < 16; it++) {
    int idx = it * 512 + t;
    int row = idx >> 7, c4 = idx & 127;
    int byte = (row * 1024 + c4 * 8) ^ ((row & 7) << 4);
    *(short4v*)((char*)sA + byte) = cvt4(L[it]);
  }
#pragma unroll
  for (int j = 0; j < 5; j++) {
    int m = j * 512 + t;
    int col = m >> 2, kslot = m & 3;
    int slot = kslot ^ (col & 3) ^ ((col >> 2) & 3);
    *(short8v*)((char*)bbuf + col * 64 + (slot << 4)) = breg[j];
  }
  __syncthreads();   // bar1

  f32x4 acc[2][10];
#pragma unroll
  for (int i = 0; i < 2; i++)
#pragma unroll
    for (int f = 0; f < 10; f++) acc[i][f] = (f32x4){0.f, 0.f, 0.f, 0.f};

#pragma unroll 1
  for (int ks = 0; ks < 16; ks++) {
    if (ks < 15) {
#pragma unroll
      for (int j = 0; j < 5; j++) {
        int m = j * 512 + t;
        int col = m >> 2, kslot = m & 3;
        breg[j] = *(const short8v*)(W0cat + (size_t)col * SDIM + (ks + 1) * 32 + kslot * 8);
      }
    }
    const char* rb = (const char*)bbuf + (ks & 1) * 40960;
    short8v af0, af1;
    {
      int row = rg * 32 + lrow;
      af0 = *(const short8v*)((const char*)sA + ((row * 1024 + ks * 64 + lk * 16) ^ ((row & 7) << 4)));
      row = rg * 32 + 16 + lrow;
      af1 = *(const short8v*)((const char*)sA + ((row * 1024 + ks * 64 + lk * 16) ^ ((row & 7) << 4)));
    }
#pragma unroll
    for (int cf = 0; cf < 10; cf++) {
      int col = colbase + cf * 16 + lrow;
      int slot = lk ^ (col & 3) ^ ((col >> 2) & 3);
      short8v b = *(const short8v*)(rb + col * 64 + (slot << 4));
      acc[0][cf] = __builtin_amdgcn_mfma_f32_16x16x32_bf16(af0, b, acc[0][cf], 0, 0, 0);
      acc[1][cf] = __builtin_amdgcn_mfma_f32_16x16x32_bf16(af1, b, acc[1][cf], 0, 0, 0);
    }
    if (ks < 15) {
      char* wb = (char*)bbuf + ((ks + 1) & 1) * 40960;
#pragma unroll
      for (int j = 0; j < 5; j++) {
        int m = j * 512 + t;
        int col = m >> 2, kslot = m & 3;
        int slot = kslot ^ (col & 3) ^ ((col >> 2) & 3);
        *(short8v*)(wb + col * 64 + (slot << 4)) = breg[j];
      }
    }
    __syncthreads();
  }

  // ---- epilogue: heads by column range ----
  {
    float vs[2][4];
#pragma unroll
    for (int i = 0; i < 2; i++)
#pragma unroll
      for (int rr = 0; rr < 4; rr++) vs[i][rr] = 0.f;

#pragma unroll
    for (int cf = 0; cf < 10; cf++) {
      int cb  = colbase + cf * 16;
      int col = cb + lrow;
      if (cb < 512) {
        float bv = (cb < 256) ? b1_0[col] : bf_0[col - 256];
#pragma unroll
        for (int i = 0; i < 2; i++)
#pragma unroll
          for (int rr = 0; rr < 4; rr++) {
            int row = rg * 32 + i * 16 + lk * 4 + rr;
            float v = fmaxf(acc[i][cf][rr] + bv, 0.f);
            int byte = (row * 1024 + col * 2) ^ ((row & 7) << 4);
            *(unsigned short*)((char*)sA + byte) = f2bf(v);
          }
      } else if (cb < 576) {
        int e = col - 512;
        float bv = hb_b[e];
#pragma unroll
        for (int i = 0; i < 2; i++)
#pragma unroll
          for (int rr = 0; rr < 4; rr++) {
            int row = rg * 32 + i * 16 + lk * 4 + rr;
            b1h[(size_t)(r0 + row) * EDIM + e] = f2bf(acc[i][cf][rr] + bv);
          }
      } else {
        int e = col - 576;
        float bv = v0_b[e], wv = v2_w[e];
#pragma unroll
        for (int i = 0; i < 2; i++)
#pragma unroll
          for (int rr = 0; rr < 4; rr++)
            vs[i][rr] = fmaf(fmaxf(acc[i][cf][rr] + bv, 0.f), wv, vs[i][rr]);
      }
    }
    if (ch == 3) {
#pragma unroll
      for (int i = 0; i < 2; i++)
#pragma unroll
        for (int rr = 0; rr < 4; rr++) {
          float v = vs[i][rr];
#pragma unroll
          for (int m = 1; m < 16; m <<= 1) v += __shfl_xor(v, m, 64);
          if (lrow == 0) vbuf[r0 + rg * 32 + i * 16 + lk * 4 + rr] = v;
        }
    }
  }
  __syncthreads();   // h-tile complete

  // ---- wf head ----
  {
    const int wr2 = wave >> 1;
    const int wc2 = wave & 1;
    f32x4 wfa[2];
    wfa[0] = (f32x4){0.f, 0.f, 0.f, 0.f};
    wfa[1] = (f32x4){0.f, 0.f, 0.f, 0.f};
    const int row = wr2 * 16 + lrow;
#pragma unroll
    for (int kf = 0; kf < 8; kf++) {
      int byte = (row * 1024 + 512 + kf * 64 + lk * 16) ^ ((row & 7) << 4);
      short8v af2 = *(const short8v*)((const char*)sA + byte);
#pragma unroll
      for (int j = 0; j < 2; j++) {
        short8v bf2v = *(const short8v*)(wf2b + (size_t)(wc2 * 32 + j * 16 + lrow) * HD + kf * 32 + 8 * lk);
        wfa[j] = __builtin_amdgcn_mfma_f32_16x16x32_bf16(af2, bf2v, wfa[j], 0, 0, 0);
      }
    }
#pragma unroll
    for (int j = 0; j < 2; j++) {
      int e = wc2 * 32 + j * 16 + lrow;
#pragma unroll
      for (int r = 0; r < 4; r++) {
        int row2 = wr2 * 16 + lk * 4 + r;
        wfinh[(size_t)(r0 + row2) * EDIM + e] = f2bf(fabsf(wfa[j][r] + bf_2[e]));
      }
    }
  }

  // ---- h1 repack to HBM ----
  {
    char* dst = (char*)h1g + (size_t)r0 * 512;
#pragma unroll
    for (int u = 0; u < 4; u++) {
      int idx = u * 512 + t;
      int row = idx >> 5;
      int p   = (idx & 31) * 16;
      short8v v = *(const short8v*)((const char*)sA + row * 1024 + p);
      *(short8v*)(dst + row * 512 + p) = v;
    }
  }
}

// ---------------- K2: gemm2 + mix, 128-row blocks, LDS-dbuf agents (r9 verbatim) ----------------
__global__ __launch_bounds__(512, 1) void qmix_k2(
    const unsigned short* __restrict__ h1g, const unsigned short* __restrict__ w12b,
    const float* __restrict__ agent_qs, const float* __restrict__ b1_2,
    const unsigned short* __restrict__ b1h, const unsigned short* __restrict__ wfinh,
    const float* __restrict__ vbuf, const float* __restrict__ v2_b,
    float* __restrict__ out)
{
  __shared__ unsigned char h1s[128 * 512];     // 64 KB (pre-swizzled bf16 [128][256])
  __shared__ unsigned short bbuf[2][16384];    // 64 KB agent-tile dbuf (swizzled)
  __shared__ float q_t[NAG * 136];             // 17.4 KB q^T [agent][row]
  __shared__ float ypart[2][128];              // 1 KB

  const int t    = threadIdx.x;
  const int r0   = blockIdx.x * 128;
  const int wave = t >> 6, lane = t & 63;
  const int lrow = lane & 15, lk = lane >> 4;
  const int wr = wave >> 1;    // row-quarter 0..3 (32 rows each)
  const int wc = wave & 1;     // e-half

  short8v Lh[8];
  {
    const char* src = (const char*)h1g + (size_t)r0 * 512;
#pragma unroll
    for (int it = 0; it < 8; it++)
      Lh[it] = *(const short8v*)(src + (it * 512 + t) * 16);
  }
  const float4* gq = (const float4*)(agent_qs + (size_t)r0 * NAG);
  float4 q0 = gq[t], q1 = gq[512 + t];
  short8v sreg[4];
#pragma unroll
  for (int rd = 0; rd < 4; rd++)
    sreg[rd] = *(const short8v*)(w12b + rd * 4096 + t * 8);   // agent 0

  {
#pragma unroll
    for (int it = 0; it < 8; it++)
      *(short8v*)(h1s + (it * 512 + t) * 16) = Lh[it];
    int row0 = t >> 3, a4 = (t & 7) * 4;
    q_t[(a4 + 0) * 136 + row0] = q0.x;
    q_t[(a4 + 1) * 136 + row0] = q0.y;
    q_t[(a4 + 2) * 136 + row0] = q0.z;
    q_t[(a4 + 3) * 136 + row0] = q0.w;
    int row1 = 64 + row0;
    q_t[(a4 + 0) * 136 + row1] = q1.x;
    q_t[(a4 + 1) * 136 + row1] = q1.y;
    q_t[(a4 + 2) * 136 + row1] = q1.z;
    q_t[(a4 + 3) * 136 + row1] = q1.w;
#pragma unroll
    for (int rd = 0; rd < 4; rd++) {
      int Lo = rd * 8192 + t * 16;
      *(short8v*)((char*)bbuf + (Lo ^ (((Lo >> 9) & 7) << 4))) = sreg[rd];
    }
  }
  __syncthreads();   // bar1

  short8v afr[2][8];
#pragma unroll
  for (int i = 0; i < 2; i++) {
    int row = wr * 32 + i * 16 + lrow;
#pragma unroll
    for (int kf = 0; kf < 8; kf++)
      afr[i][kf] = *(const short8v*)(h1s + row * 512 + ((kf * 64 + lk * 16) ^ ((row & 7) << 4)));
  }

  f32x4 hac00 = (f32x4){0.f,0.f,0.f,0.f}, hac01 = (f32x4){0.f,0.f,0.f,0.f};
  f32x4 hac10 = (f32x4){0.f,0.f,0.f,0.f}, hac11 = (f32x4){0.f,0.f,0.f,0.f};

#pragma unroll 1
  for (int a = 0; a < NAG; a++) {
    if (a < NAG - 1) {
      const unsigned short* p = w12b + (size_t)(a + 1) * 16384;
#pragma unroll
      for (int rd = 0; rd < 4; rd++)
        sreg[rd] = *(const short8v*)(p + rd * 4096 + t * 8);
    }
    const char* rbase = (const char*)bbuf + (a & 1) * 32768;

    f32x4 T00 = (f32x4){0.f,0.f,0.f,0.f}, T01 = (f32x4){0.f,0.f,0.f,0.f};
    f32x4 T10 = (f32x4){0.f,0.f,0.f,0.f}, T11 = (f32x4){0.f,0.f,0.f,0.f};
    const int e0 = wc * 32 + lrow, e1 = e0 + 16;
#pragma unroll
    for (int kf = 0; kf < 8; kf++) {
      short8v b0  = *(const short8v*)(rbase + ((e0 * 512 + kf * 64 + lk * 16) ^ ((e0 & 7) << 4)));
      short8v b1v = *(const short8v*)(rbase + ((e1 * 512 + kf * 64 + lk * 16) ^ ((e1 & 7) << 4)));
      T00 = __builtin_amdgcn_mfma_f32_16x16x32_bf16(afr[0][kf], b0,  T00, 0, 0, 0);
      T10 = __builtin_amdgcn_mfma_f32_16x16x32_bf16(afr[1][kf], b0,  T10, 0, 0, 0);
      T01 = __builtin_amdgcn_mfma_f32_16x16x32_bf16(afr[0][kf], b1v, T01, 0, 0, 0);
      T11 = __builtin_amdgcn_mfma_f32_16x16x32_bf16(afr[1][kf], b1v, T11, 0, 0, 0);
    }
    float bb0 = b1_2[a * EDIM + e0];
    float bb1 = b1_2[a * EDIM + e1];
    float4 qa = *(const float4*)(&q_t[a * 136 + wr * 32 + lk * 4]);
    float4 qb = *(const float4*)(&q_t[a * 136 + wr * 32 + 16 + lk * 4]);
#pragma unroll
    for (int r = 0; r < 4; r++) {
      float qar = (r == 0) ? qa.x : (r == 1) ? qa.y : (r == 2) ? qa.z : qa.w;
      float qbr = (r == 0) ? qb.x : (r == 1) ? qb.y : (r == 2) ? qb.z : qb.w;
      hac00[r] = fmaf(qar, fabsf(T00[r] + bb0), hac00[r]);
      hac01[r] = fmaf(qar, fabsf(T01[r] + bb1), hac01[r]);
      hac10[r] = fmaf(qbr, fabsf(T10[r] + bb0), hac10[r]);
      hac11[r] = fmaf(qbr, fabsf(T11[r] + bb1), hac11[r]);
    }
    if (a < NAG - 1) {
      char* wb = (char*)bbuf + ((a & 1) ^ 1) * 32768;
#pragma unroll
      for (int rd = 0; rd < 4; rd++) {
        int Lo = rd * 8192 + t * 16;
        *(short8v*)(wb + (Lo ^ (((Lo >> 9) & 7) << 4))) = sreg[rd];
      }
    }
    __syncthreads();
  }

  // epilogue
  {
    float ys0[4], ys1[4];
    const int e0 = wc * 32 + lrow, e1 = e0 + 16;
#pragma unroll
    for (int r = 0; r < 4; r++) {
      int row0 = wr * 32 + lk * 4 + r;
      int row1 = row0 + 16;
      size_t g0 = (size_t)(r0 + row0) * EDIM;
      size_t g1 = (size_t)(r0 + row1) * EDIM;
      float p00 = hac00[r] + bf2f(b1h[g0 + e0]);
      float p01 = hac01[r] + bf2f(b1h[g0 + e1]);
      float p10 = hac10[r] + bf2f(b1h[g1 + e0]);
      float p11 = hac11[r] + bf2f(b1h[g1 + e1]);
      float h00 = p00 > 0.f ? p00 : expm1f(p00);
      float h01 = p01 > 0.f ? p01 : expm1f(p01);
      float h10 = p10 > 0.f ? p10 : expm1f(p10);
      float h11 = p11 > 0.f ? p11 : expm1f(p11);
      ys0[r] = h00 * bf2f(wfinh[g0 + e0]) + h01 * bf2f(wfinh[g0 + e1]);
      ys1[r] = h10 * bf2f(wfinh[g1 + e0]) + h11 * bf2f(wfinh[g1 + e1]);
    }
#pragma unroll
    for (int m = 1; m < 16; m <<= 1)
#pragma unroll
      for (int r = 0; r < 4; r++) {
        ys0[r] += __shfl_xor(ys0[r], m, 64);
        ys1[r] += __shfl_xor(ys1[r], m, 64);
      }
    if (lrow == 0) {
#pragma unroll
      for (int r = 0; r < 4; r++) {
        ypart[wc][wr * 32 + lk * 4 + r]      = ys0[r];
        ypart[wc][wr * 32 + 16 + lk * 4 + r] = ys1[r];
      }
    }
  }
  __syncthreads();
  if (t < 128) {
    out[r0 + t] = ypart[0][t] + ypart[1][t] + vbuf[r0 + t] + v2_b[0];
  }
}

extern "C" void kernel_launch(void* const* d_in, const int* in_sizes, int n_in,
                              void* d_out, int out_size, void* d_ws, size_t ws_size,
                              hipStream_t stream) {
  const float* agent_qs = (const float*)d_in[0];
  const float* states   = (const float*)d_in[1];
  const float* w1_0 = (const float*)d_in[2];
  const float* b1_0 = (const float*)d_in[3];
  const float* w1_2 = (const float*)d_in[4];
  const float* b1_2 = (const float*)d_in[5];
  const float* wf_0 = (const float*)d_in[6];
  const float* bf_0 = (const float*)d_in[7];
  const float* wf_2 = (const float*)d_in[8];
  const float* bf_2 = (const float*)d_in[9];
  const float* hb_w = (const float*)d_in[10];
  const float* hb_b = (const float*)d_in[11];
  const float* v0_w = (const float*)d_in[12];
  const float* v0_b = (const float*)d_in[13];
  const float* v2_w = (const float*)d_in[14];
  const float* v2_b = (const float*)d_in[15];

  char* ws = (char*)d_ws;
  unsigned short* W0cat = (unsigned short*)ws;                  //    655,360 B
  unsigned short* w12b  = (unsigned short*)(ws + 655360);       //  1,048,576 B
  unsigned short* wf2b  = (unsigned short*)(ws + 1703936);      //     32,768 B
  unsigned short* h1g   = (unsigned short*)(ws + 1736704);      // 16,777,216 B
  unsigned short* b1h   = (unsigned short*)(ws + 18513920);     //  4,194,304 B
  unsigned short* wfinh = (unsigned short*)(ws + 22708224);     //  4,194,304 B
  float*          vbuf  = (float*)(ws + 26902528);              //    131,072 B

  qmix_convert<<<3392, 256, 0, stream>>>(w1_0, wf_0, hb_w, v0_w, w1_2, wf_2,
                                         W0cat, w12b, wf2b);
  qmix_k1<<<512, 512, 0, stream>>>(states, W0cat, wf2b, b1_0, bf_0, hb_b, v0_b,
                                   v2_w, bf_2, h1g, b1h, wfinh, vbuf);
  qmix_k2<<<256, 512, 0, stream>>>(h1g, w12b, agent_qs, b1_2, b1h, wfinh, vbuf,
                                   v2_b, (float*)d_out);
}

// Round 16
// 105.029 us; speedup vs baseline: 1.2338x; 1.0193x over previous
//
#include <hip/hip_runtime.h>

// QMixer — round 16: K1 at 1024 threads (4 waves/SIMD — the untried lever).
// r15 counters: K1 64us with MfmaUtil 13% + VALUBusy 17% + HBM 12% -> ~70% of
// cycles idle = latency-bound at 2 waves/SIMD (every K1 variant so far ran
// 1 block/CU x 8 waves). This round: same 64-row tile, same grid, same B-dbuf
// traffic, but 16 waves/block -> 4 waves/SIMD. Wave tile 32x80, acc[2][5]=40
// AGPR + ~60 VGPR = ~100 unified <= 128 cap (no spill). Slot-XOR kept (no
// cost); conflicts shown to be A-path (r13==r15 count), secondary (~5us).
// K2 = r9 verbatim (~35us, at its LDS-BW floor). convert unchanged.

#define SDIM 512
#define HD   256
#define EDIM 64
#define NAG  32

typedef short short8v __attribute__((ext_vector_type(8)));
typedef short short4v __attribute__((ext_vector_type(4)));
typedef float f32x4  __attribute__((ext_vector_type(4)));

__device__ __forceinline__ unsigned short f2bf(float f) {
  unsigned int u = __float_as_uint(f);
  unsigned int r = (u + 0x7FFFu + ((u >> 16) & 1u)) >> 16;
  return (unsigned short)r;
}
__device__ __forceinline__ float bf2f(unsigned short u) {
  return __uint_as_float(((unsigned int)u) << 16);
}
__device__ __forceinline__ short4v cvt4(float4 a) {
  short4v r;
  r[0] = (short)f2bf(a.x); r[1] = (short)f2bf(a.y);
  r[2] = (short)f2bf(a.z); r[3] = (short)f2bf(a.w);
  return r;
}

// ---------------- convert weights to bf16 ----------------
__global__ void qmix_convert(const float* __restrict__ w1_0, const float* __restrict__ wf_0,
                             const float* __restrict__ hb_w, const float* __restrict__ v0_w,
                             const float* __restrict__ w1_2, const float* __restrict__ wf_2,
                             unsigned short* __restrict__ W0cat, unsigned short* __restrict__ w12b,
                             unsigned short* __restrict__ wf2b) {
  int i = blockIdx.x * 256 + threadIdx.x;
  if (i < 327680) {
    float v;
    if (i < 131072)      v = w1_0[i];
    else if (i < 262144) v = wf_0[i - 131072];
    else if (i < 294912) v = hb_w[i - 262144];
    else                 v = v0_w[i - 294912];
    W0cat[i] = f2bf(v);
  } else if (i < 851968) {
    w12b[i - 327680] = f2bf(w1_2[i - 327680]);
  } else if (i < 868352) {
    wf2b[i - 851968] = f2bf(wf_2[i - 851968]);
  }
}

// ---------------- K1: gemm1 + wf + heads, 64-row blocks, 1024 threads ----------------
__global__ __launch_bounds__(1024, 1) void qmix_k1(
    const float* __restrict__ states, const unsigned short* __restrict__ W0cat,
    const unsigned short* __restrict__ wf2b,
    const float* __restrict__ b1_0, const float* __restrict__ bf_0,
    const float* __restrict__ hb_b, const float* __restrict__ v0_b,
    const float* __restrict__ v2_w, const float* __restrict__ bf_2,
    unsigned short* __restrict__ h1g, unsigned short* __restrict__ b1h,
    unsigned short* __restrict__ wfinh, float* __restrict__ vbuf)
{
  __shared__ unsigned short sA[64 * 512];      // 64 KB: states, then h1|hf (swizzled)
  __shared__ unsigned short bbuf[2][20480];    // 80 KB: B k-slice dbuf, slot-XOR swz

  const int t    = threadIdx.x;
  const int r0   = blockIdx.x * 64;
  const int wave = t >> 6, lane = t & 63;
  const int lrow = lane & 15, lk = lane >> 4;
  const int rg = wave >> 3;      // row-half 0..1 (32 rows)
  const int ch = wave & 7;       // col-octant 0..7 (80 cols)
  const int colbase = ch * 80;

  // ---- phase 0: issue all loads (states + B slice 0) ----
  const float4* gS4 = (const float4*)(states + (size_t)r0 * SDIM);
  float4 L[8];
#pragma unroll
  for (int it = 0; it < 8; it++) L[it] = gS4[it * 1024 + t];

  short8v breg[3];
#pragma unroll
  for (int j = 0; j < 3; j++) {
    int m = j * 1024 + t;               // 2560 chunks of 16B = 40 KB
    if (m < 2560) {
      int col = m >> 2, kslot = m & 3;
      breg[j] = *(const short8v*)(W0cat + (size_t)col * SDIM + kslot * 8);
    }
  }

#pragma unroll
  for (int it = 0; it < 8; it++) {
    int idx = it * 1024 + t;
    int row = idx >> 7, c4 = idx & 127;
    int byte = (row * 1024 + c4 * 8) ^ ((row & 7) << 4);
    *(short4v*)((char*)sA + byte) = cvt4(L[it]);
  }
#pragma unroll
  for (int j = 0; j < 3; j++) {
    int m = j * 1024 + t;
    if (m < 2560) {
      int col = m >> 2, kslot = m & 3;
      int slot = kslot ^ (col & 3) ^ ((col >> 2) & 3);
      *(short8v*)((char*)bbuf + col * 64 + (slot << 4)) = breg[j];
    }
  }
  __syncthreads();   // bar1: states + B slice 0 staged

  // ---- k-loop: acc[2][5], wave tile 32 rows x 80 cols ----
  f32x4 acc[2][5];
#pragma unroll
  for (int i = 0; i < 2; i++)
#pragma unroll
    for (int f = 0; f < 5; f++) acc[i][f] = (f32x4){0.f, 0.f, 0.f, 0.f};

#pragma unroll 1
  for (int ks = 0; ks < 16; ks++) {
    if (ks < 15) {
#pragma unroll
      for (int j = 0; j < 3; j++) {
        int m = j * 1024 + t;
        if (m < 2560) {
          int col = m >> 2, kslot = m & 3;
          breg[j] = *(const short8v*)(W0cat + (size_t)col * SDIM + (ks + 1) * 32 + kslot * 8);
        }
      }
    }
    const char* rb = (const char*)bbuf + (ks & 1) * 40960;
    short8v af0, af1;
    {
      int row = rg * 32 + lrow;
      af0 = *(const short8v*)((const char*)sA + ((row * 1024 + ks * 64 + lk * 16) ^ ((row & 7) << 4)));
      row = rg * 32 + 16 + lrow;
      af1 = *(const short8v*)((const char*)sA + ((row * 1024 + ks * 64 + lk * 16) ^ ((row & 7) << 4)));
    }
#pragma unroll
    for (int cf = 0; cf < 5; cf++) {
      int col = colbase + cf * 16 + lrow;
      int slot = lk ^ (col & 3) ^ ((col >> 2) & 3);
      short8v b = *(const short8v*)(rb + col * 64 + (slot << 4));
      acc[0][cf] = __builtin_amdgcn_mfma_f32_16x16x32_bf16(af0, b, acc[0][cf], 0, 0, 0);
      acc[1][cf] = __builtin_amdgcn_mfma_f32_16x16x32_bf16(af1, b, acc[1][cf], 0, 0, 0);
    }
    if (ks < 15) {
      char* wb = (char*)bbuf + ((ks + 1) & 1) * 40960;
#pragma unroll
      for (int j = 0; j < 3; j++) {
        int m = j * 1024 + t;
        if (m < 2560) {
          int col = m >> 2, kslot = m & 3;
          int slot = kslot ^ (col & 3) ^ ((col >> 2) & 3);
          *(short8v*)(wb + col * 64 + (slot << 4)) = breg[j];
        }
      }
    }
    __syncthreads();
  }

  // ---- epilogue: heads by column range, h written back into sA ----
  {
    float vs[2][4];
#pragma unroll
    for (int i = 0; i < 2; i++)
#pragma unroll
      for (int rr = 0; rr < 4; rr++) vs[i][rr] = 0.f;

#pragma unroll
    for (int cf = 0; cf < 5; cf++) {
      int cb  = colbase + cf * 16;   // wave-uniform
      int col = cb + lrow;
      if (cb < 512) {
        float bv = (cb < 256) ? b1_0[col] : bf_0[col - 256];
#pragma unroll
        for (int i = 0; i < 2; i++)
#pragma unroll
          for (int rr = 0; rr < 4; rr++) {
            int row = rg * 32 + i * 16 + lk * 4 + rr;
            float v = fmaxf(acc[i][cf][rr] + bv, 0.f);
            int byte = (row * 1024 + col * 2) ^ ((row & 7) << 4);
            *(unsigned short*)((char*)sA + byte) = f2bf(v);
          }
      } else if (cb < 576) {
        int e = col - 512;
        float bv = hb_b[e];
#pragma unroll
        for (int i = 0; i < 2; i++)
#pragma unroll
          for (int rr = 0; rr < 4; rr++) {
            int row = rg * 32 + i * 16 + lk * 4 + rr;
            b1h[(size_t)(r0 + row) * EDIM + e] = f2bf(acc[i][cf][rr] + bv);
          }
      } else {
        int e = col - 576;
        float bv = v0_b[e], wv = v2_w[e];
#pragma unroll
        for (int i = 0; i < 2; i++)
#pragma unroll
          for (int rr = 0; rr < 4; rr++)
            vs[i][rr] = fmaf(fmaxf(acc[i][cf][rr] + bv, 0.f), wv, vs[i][rr]);
      }
    }
    if (ch == 7) {    // v-head owner (cols 576..639)
#pragma unroll
      for (int i = 0; i < 2; i++)
#pragma unroll
        for (int rr = 0; rr < 4; rr++) {
          float v = vs[i][rr];
#pragma unroll
          for (int m = 1; m < 16; m <<= 1) v += __shfl_xor(v, m, 64);
          if (lrow == 0) vbuf[r0 + rg * 32 + i * 16 + lk * 4 + rr] = v;
        }
    }
  }
  __syncthreads();   // h-tile complete

  // ---- wf head: 16 waves = 4 row-frags x 4 e-frags over 64 rows x 64 cols ----
  {
    const int wr2 = wave >> 2;     // 0..3
    const int ec  = wave & 3;      // 0..3
    f32x4 wfa = (f32x4){0.f, 0.f, 0.f, 0.f};
    const int row = wr2 * 16 + lrow;
#pragma unroll
    for (int kf = 0; kf < 8; kf++) {
      int byte = (row * 1024 + 512 + kf * 64 + lk * 16) ^ ((row & 7) << 4);
      short8v af2 = *(const short8v*)((const char*)sA + byte);
      short8v bf2v = *(const short8v*)(wf2b + (size_t)(ec * 16 + lrow) * HD + kf * 32 + 8 * lk);
      wfa = __builtin_amdgcn_mfma_f32_16x16x32_bf16(af2, bf2v, wfa, 0, 0, 0);
    }
    int e = ec * 16 + lrow;
#pragma unroll
    for (int r = 0; r < 4; r++) {
      int row2 = wr2 * 16 + lk * 4 + r;
      wfinh[(size_t)(r0 + row2) * EDIM + e] = f2bf(fabsf(wfa[r] + bf_2[e]));
    }
  }

  // ---- h1 repack to HBM (swizzle baked into layout) ----
  {
    char* dst = (char*)h1g + (size_t)r0 * 512;
#pragma unroll
    for (int u = 0; u < 2; u++) {
      int idx = u * 1024 + t;          // 2048 chunks of 16B
      int row = idx >> 5;
      int p   = (idx & 31) * 16;
      short8v v = *(const short8v*)((const char*)sA + row * 1024 + p);
      *(short8v*)(dst + row * 512 + p) = v;
    }
  }
}

// ---------------- K2: gemm2 + mix, 128-row blocks, LDS-dbuf agents (r9 verbatim) ----------------
__global__ __launch_bounds__(512, 1) void qmix_k2(
    const unsigned short* __restrict__ h1g, const unsigned short* __restrict__ w12b,
    const float* __restrict__ agent_qs, const float* __restrict__ b1_2,
    const unsigned short* __restrict__ b1h, const unsigned short* __restrict__ wfinh,
    const float* __restrict__ vbuf, const float* __restrict__ v2_b,
    float* __restrict__ out)
{
  __shared__ unsigned char h1s[128 * 512];     // 64 KB (pre-swizzled bf16 [128][256])
  __shared__ unsigned short bbuf[2][16384];    // 64 KB agent-tile dbuf (swizzled)
  __shared__ float q_t[NAG * 136];             // 17.4 KB q^T [agent][row]
  __shared__ float ypart[2][128];              // 1 KB

  const int t    = threadIdx.x;
  const int r0   = blockIdx.x * 128;
  const int wave = t >> 6, lane = t & 63;
  const int lrow = lane & 15, lk = lane >> 4;
  const int wr = wave >> 1;    // row-quarter 0..3 (32 rows each)
  const int wc = wave & 1;     // e-half

  short8v Lh[8];
  {
    const char* src = (const char*)h1g + (size_t)r0 * 512;
#pragma unroll
    for (int it = 0; it < 8; it++)
      Lh[it] = *(const short8v*)(src + (it * 512 + t) * 16);
  }
  const float4* gq = (const float4*)(agent_qs + (size_t)r0 * NAG);
  float4 q0 = gq[t], q1 = gq[512 + t];
  short8v sreg[4];
#pragma unroll
  for (int rd = 0; rd < 4; rd++)
    sreg[rd] = *(const short8v*)(w12b + rd * 4096 + t * 8);   // agent 0

  {
#pragma unroll
    for (int it = 0; it < 8; it++)
      *(short8v*)(h1s + (it * 512 + t) * 16) = Lh[it];
    int row0 = t >> 3, a4 = (t & 7) * 4;
    q_t[(a4 + 0) * 136 + row0] = q0.x;
    q_t[(a4 + 1) * 136 + row0] = q0.y;
    q_t[(a4 + 2) * 136 + row0] = q0.z;
    q_t[(a4 + 3) * 136 + row0] = q0.w;
    int row1 = 64 + row0;
    q_t[(a4 + 0) * 136 + row1] = q1.x;
    q_t[(a4 + 1) * 136 + row1] = q1.y;
    q_t[(a4 + 2) * 136 + row1] = q1.z;
    q_t[(a4 + 3) * 136 + row1] = q1.w;
#pragma unroll
    for (int rd = 0; rd < 4; rd++) {
      int Lo = rd * 8192 + t * 16;
      *(short8v*)((char*)bbuf + (Lo ^ (((Lo >> 9) & 7) << 4))) = sreg[rd];
    }
  }
  __syncthreads();   // bar1

  short8v afr[2][8];
#pragma unroll
  for (int i = 0; i < 2; i++) {
    int row = wr * 32 + i * 16 + lrow;
#pragma unroll
    for (int kf = 0; kf < 8; kf++)
      afr[i][kf] = *(const short8v*)(h1s + row * 512 + ((kf * 64 + lk * 16) ^ ((row & 7) << 4)));
  }

  f32x4 hac00 = (f32x4){0.f,0.f,0.f,0.f}, hac01 = (f32x4){0.f,0.f,0.f,0.f};
  f32x4 hac10 = (f32x4){0.f,0.f,0.f,0.f}, hac11 = (f32x4){0.f,0.f,0.f,0.f};

#pragma unroll 1
  for (int a = 0; a < NAG; a++) {
    if (a < NAG - 1) {
      const unsigned short* p = w12b + (size_t)(a + 1) * 16384;
#pragma unroll
      for (int rd = 0; rd < 4; rd++)
        sreg[rd] = *(const short8v*)(p + rd * 4096 + t * 8);
    }
    const char* rbase = (const char*)bbuf + (a & 1) * 32768;

    f32x4 T00 = (f32x4){0.f,0.f,0.f,0.f}, T01 = (f32x4){0.f,0.f,0.f,0.f};
    f32x4 T10 = (f32x4){0.f,0.f,0.f,0.f}, T11 = (f32x4){0.f,0.f,0.f,0.f};
    const int e0 = wc * 32 + lrow, e1 = e0 + 16;
#pragma unroll
    for (int kf = 0; kf < 8; kf++) {
      short8v b0  = *(const short8v*)(rbase + ((e0 * 512 + kf * 64 + lk * 16) ^ ((e0 & 7) << 4)));
      short8v b1v = *(const short8v*)(rbase + ((e1 * 512 + kf * 64 + lk * 16) ^ ((e1 & 7) << 4)));
      T00 = __builtin_amdgcn_mfma_f32_16x16x32_bf16(afr[0][kf], b0,  T00, 0, 0, 0);
      T10 = __builtin_amdgcn_mfma_f32_16x16x32_bf16(afr[1][kf], b0,  T10, 0, 0, 0);
      T01 = __builtin_amdgcn_mfma_f32_16x16x32_bf16(afr[0][kf], b1v, T01, 0, 0, 0);
      T11 = __builtin_amdgcn_mfma_f32_16x16x32_bf16(afr[1][kf], b1v, T11, 0, 0, 0);
    }
    float bb0 = b1_2[a * EDIM + e0];
    float bb1 = b1_2[a * EDIM + e1];
    float4 qa = *(const float4*)(&q_t[a * 136 + wr * 32 + lk * 4]);
    float4 qb = *(const float4*)(&q_t[a * 136 + wr * 32 + 16 + lk * 4]);
#pragma unroll
    for (int r = 0; r < 4; r++) {
      float qar = (r == 0) ? qa.x : (r == 1) ? qa.y : (r == 2) ? qa.z : qa.w;
      float qbr = (r == 0) ? qb.x : (r == 1) ? qb.y : (r == 2) ? qb.z : qb.w;
      hac00[r] = fmaf(qar, fabsf(T00[r] + bb0), hac00[r]);
      hac01[r] = fmaf(qar, fabsf(T01[r] + bb1), hac01[r]);
      hac10[r] = fmaf(qbr, fabsf(T10[r] + bb0), hac10[r]);
      hac11[r] = fmaf(qbr, fabsf(T11[r] + bb1), hac11[r]);
    }
    if (a < NAG - 1) {
      char* wb = (char*)bbuf + ((a & 1) ^ 1) * 32768;
#pragma unroll
      for (int rd = 0; rd < 4; rd++) {
        int Lo = rd * 8192 + t * 16;
        *(short8v*)(wb + (Lo ^ (((Lo >> 9) & 7) << 4))) = sreg[rd];
      }
    }
    __syncthreads();
  }

  // epilogue
  {
    float ys0[4], ys1[4];
    const int e0 = wc * 32 + lrow, e1 = e0 + 16;
#pragma unroll
    for (int r = 0; r < 4; r++) {
      int row0 = wr * 32 + lk * 4 + r;
      int row1 = row0 + 16;
      size_t g0 = (size_t)(r0 + row0) * EDIM;
      size_t g1 = (size_t)(r0 + row1) * EDIM;
      float p00 = hac00[r] + bf2f(b1h[g0 + e0]);
      float p01 = hac01[r] + bf2f(b1h[g0 + e1]);
      float p10 = hac10[r] + bf2f(b1h[g1 + e0]);
      float p11 = hac11[r] + bf2f(b1h[g1 + e1]);
      float h00 = p00 > 0.f ? p00 : expm1f(p00);
      float h01 = p01 > 0.f ? p01 : expm1f(p01);
      float h10 = p10 > 0.f ? p10 : expm1f(p10);
      float h11 = p11 > 0.f ? p11 : expm1f(p11);
      ys0[r] = h00 * bf2f(wfinh[g0 + e0]) + h01 * bf2f(wfinh[g0 + e1]);
      ys1[r] = h10 * bf2f(wfinh[g1 + e0]) + h11 * bf2f(wfinh[g1 + e1]);
    }
#pragma unroll
    for (int m = 1; m < 16; m <<= 1)
#pragma unroll
      for (int r = 0; r < 4; r++) {
        ys0[r] += __shfl_xor(ys0[r], m, 64);
        ys1[r] += __shfl_xor(ys1[r], m, 64);
      }
    if (lrow == 0) {
#pragma unroll
      for (int r = 0; r < 4; r++) {
        ypart[wc][wr * 32 + lk * 4 + r]      = ys0[r];
        ypart[wc][wr * 32 + 16 + lk * 4 + r] = ys1[r];
      }
    }
  }
  __syncthreads();
  if (t < 128) {
    out[r0 + t] = ypart[0][t] + ypart[1][t] + vbuf[r0 + t] + v2_b[0];
  }
}

extern "C" void kernel_launch(void* const* d_in, const int* in_sizes, int n_in,
                              void* d_out, int out_size, void* d_ws, size_t ws_size,
                              hipStream_t stream) {
  const float* agent_qs = (const float*)d_in[0];
  const float* states   = (const float*)d_in[1];
  const float* w1_0 = (const float*)d_in[2];
  const float* b1_0 = (const float*)d_in[3];
  const float* w1_2 = (const float*)d_in[4];
  const float* b1_2 = (const float*)d_in[5];
  const float* wf_0 = (const float*)d_in[6];
  const float* bf_0 = (const float*)d_in[7];
  const float* wf_2 = (const float*)d_in[8];
  const float* bf_2 = (const float*)d_in[9];
  const float* hb_w = (const float*)d_in[10];
  const float* hb_b = (const float*)d_in[11];
  const float* v0_w = (const float*)d_in[12];
  const float* v0_b = (const float*)d_in[13];
  const float* v2_w = (const float*)d_in[14];
  const float* v2_b = (const float*)d_in[15];

  char* ws = (char*)d_ws;
  unsigned short* W0cat = (unsigned short*)ws;                  //    655,360 B
  unsigned short* w12b  = (unsigned short*)(ws + 655360);       //  1,048,576 B
  unsigned short* wf2b  = (unsigned short*)(ws + 1703936);      //     32,768 B
  unsigned short* h1g   = (unsigned short*)(ws + 1736704);      // 16,777,216 B
  unsigned short* b1h   = (unsigned short*)(ws + 18513920);     //  4,194,304 B
  unsigned short* wfinh = (unsigned short*)(ws + 22708224);     //  4,194,304 B
  float*          vbuf  = (float*)(ws + 26902528);              //    131,072 B

  qmix_convert<<<3392, 256, 0, stream>>>(w1_0, wf_0, hb_w, v0_w, w1_2, wf_2,
                                         W0cat, w12b, wf2b);
  qmix_k1<<<512, 1024, 0, stream>>>(states, W0cat, wf2b, b1_0, bf_0, hb_b, v0_b,
                                    v2_w, bf_2, h1g, b1h, wfinh, vbuf);
  qmix_k2<<<256, 512, 0, stream>>>(h1g, w12b, agent_qs, b1_2, b1h, wfinh, vbuf,
                                   v2_b, (float*)d_out);
}